// Round 9
// baseline (573.971 us; speedup 1.0000x reference)
//
#include <hip/hip_runtime.h>
#include <hip/hip_bf16.h>

#define NLOG 16
#define NN 65536
#define KK 9
#define FF 32
#define OO 64
#define DD 288            // K*F
#define WSTR 296          // padded W row stride (shorts)
#define CHUNK 64          // points per block-chunk
#define THREADS 256
#define NBLOCKS 1024
#define TOTALP (8 * NN)           // 524288
#define NCHUNKS (TOTALP / CHUNK)  // 8192
#define ROUNDS (NCHUNKS / NBLOCKS)// 8 (== batch count; ci>>10 == batch)
#define RA_STRIDE 72              // shorts/point: 9 t-rows x 8 bf16 (16B rows)
#define RB_STRIDE 10              // shorts/point: k=8 column over t, +1 pad

typedef float f32x4 __attribute__((ext_vector_type(4)));
typedef float f32x2 __attribute__((ext_vector_type(2)));
typedef unsigned int u32x4 __attribute__((ext_vector_type(4)));
typedef short s16x8 __attribute__((ext_vector_type(8)));
typedef short s16x4 __attribute__((ext_vector_type(4)));

static __device__ __forceinline__ short f2bf(float f) {
    union { __hip_bfloat16 h; short s; } u;
    u.h = __float2bfloat16(f);
    return u.s;
}

// exact bf16->f32
static __device__ __forceinline__ void bf2f2(unsigned int p, float& lo, float& hi) {
    union { unsigned int u; float f; } a, b;
    a.u = p << 16;
    b.u = p & 0xFFFF0000u;
    lo = a.f; hi = b.f;
}
static __device__ __forceinline__ float bf1(unsigned short s) {
    union { unsigned int u; float f; } a;
    a.u = ((unsigned int)s) << 16;
    return a.f;
}

static __device__ __forceinline__ float elu1(float x) {
    float e = __expf(fminf(x, 0.f)) - 1.f;
    return x > 0.f ? x : e;
}

// ---- pre-kernel 1: x (f32) -> xbf (bf16), same layout ----
__global__ __launch_bounds__(THREADS) void xcvt(
    const float* __restrict__ x, unsigned short* __restrict__ xbf)
{
    const size_t i = ((size_t)blockIdx.x * THREADS + threadIdx.x) * 8;
    const f32x4 a = *(const f32x4*)(x + i);
    const f32x4 b = *(const f32x4*)(x + i + 4);
    s16x8 p;
    p[0] = f2bf(a.x); p[1] = f2bf(a.y); p[2] = f2bf(a.z); p[3] = f2bf(a.w);
    p[4] = f2bf(b.x); p[5] = f2bf(b.y); p[6] = f2bf(b.z); p[7] = f2bf(b.w);
    *(s16x8*)(xbf + i) = p;
}

// ---- pre-kernel 2: adjacency -> packed bf16 (recA: k=0..7, recB: k=8) ----
__global__ __launch_bounds__(THREADS) void adjcvt(
    const float* __restrict__ v, const float* __restrict__ aw,
    unsigned short* __restrict__ recA, unsigned short* __restrict__ recB)
{
    const int e = blockIdx.x * THREADS + threadIdx.x;   // over NN*KK exact
    const int n = e / KK;
    const int t = e - n * KK;
    const float* vr = v + n * 8;
    short o[8];
    float s8 = 0.f;
    #pragma unroll
    for (int k = 0; k < KK; ++k) {
        float s = 0.f;
        #pragma unroll
        for (int si = 0; si < 8; ++si)
            s += vr[si] * aw[si * 81 + k * 9 + t];
        if (k < 8) o[k] = f2bf(s); else s8 = s;
    }
    *(s16x8*)(recA + (size_t)n * RA_STRIDE + t * 8) = *(s16x8*)o;
    recB[(size_t)n * RB_STRIDE + t] = (unsigned short)f2bf(s8);
    if (t == 0) recB[(size_t)n * RB_STRIDE + 9] = 0;
}

// =================== pipelined main kernel (PRE path) ====================
// Theory R9: R3/R6/R8 all plateau at ~230us timed with ~60% un-hidden
// memory latency per 17k-cycle wave-chunk slot (VALU 28%, MFMA 3%).
// -> software-pipeline: gathers issued 1 chunk ahead (bf16, 36 VGPR buffer),
//    nbr indices 2 chunks ahead; adjacency is ROUND-INVARIANT (lane's vertex
//    n0 = bid*64+pl identical across the 8 batch-rounds) -> loaded ONCE.
// Grid-stride unpinned (R7: XCD-pinning thrashes per-XCD L2). No
// nontemporal (R5). Swapped MFMA + f32x4 stores (R8, validated).

#define LOADNBR(nb, ci_)                                                    \
{                                                                           \
    const int* nip_ = nbr + ((size_t)(ci_) * CHUNK + pl) * KK;              \
    _Pragma("unroll")                                                       \
    for (int k_ = 0; k_ < KK; ++k_) nb[k_] = nip_[k_];                      \
}

#define GATHER(gp, nb, ci_)                                                 \
{                                                                           \
    const unsigned short* xb_ =                                             \
        xbf + (((size_t)((ci_) >> 10)) << NLOG) * FF + fo;                  \
    _Pragma("unroll")                                                       \
    for (int k_ = 0; k_ < KK; ++k_)                                         \
        gp[k_] = *(const u32x4*)(xb_ + (size_t)nb[k_] * FF);                \
}

#define COMPUTE(gp, ci_)                                                    \
{                                                                           \
    f32x2 G2[KK][4];                                                        \
    _Pragma("unroll")                                                       \
    for (int k_ = 0; k_ < KK; ++k_) {                                       \
        float l0,h0,l1,h1,l2,h2,l3,h3;                                      \
        bf2f2(gp[k_].x, l0, h0);                                            \
        bf2f2(gp[k_].y, l1, h1);                                            \
        bf2f2(gp[k_].z, l2, h2);                                            \
        bf2f2(gp[k_].w, l3, h3);                                            \
        G2[k_][0] = f32x2{l0, h0};                                          \
        G2[k_][1] = f32x2{l1, h1};                                          \
        G2[k_][2] = f32x2{l2, h2};                                          \
        G2[k_][3] = f32x2{l3, h3};                                          \
    }                                                                       \
    f32x4 acc0 = {0,0,0,0}, acc1 = {0,0,0,0};                               \
    f32x4 acc2 = {0,0,0,0}, acc3 = {0,0,0,0};                               \
    _Pragma("unroll")                                                       \
    for (int t_ = 0; t_ < KK; ++t_) {                                       \
        float a_[KK];                                                       \
        bf2f2(adjP[t_].x, a_[0], a_[1]);                                    \
        bf2f2(adjP[t_].y, a_[2], a_[3]);                                    \
        bf2f2(adjP[t_].z, a_[4], a_[5]);                                    \
        bf2f2(adjP[t_].w, a_[6], a_[7]);                                    \
        a_[8] = rbf[t_];                                                    \
        f32x2 xn2[4] = {{0,0},{0,0},{0,0},{0,0}};                           \
        _Pragma("unroll")                                                   \
        for (int k_ = 0; k_ < KK; ++k_) {                                   \
            const f32x2 ak_ = {a_[k_], a_[k_]};                             \
            _Pragma("unroll")                                               \
            for (int i_ = 0; i_ < 4; ++i_) xn2[i_] += G2[k_][i_] * ak_;     \
        }                                                                   \
        s16x8 af;                                                           \
        _Pragma("unroll")                                                   \
        for (int i_ = 0; i_ < 4; ++i_) {                                    \
            af[2*i_]   = f2bf(elu1(xn2[i_].x));                             \
            af[2*i_+1] = f2bf(elu1(xn2[i_].y));                             \
        }                                                                   \
        const short* wrow_ = &Wl[l15 * WSTR + t_ * FF + fo];                \
        s16x8 b0_ = *(const s16x8*)(wrow_);                                 \
        s16x8 b1_ = *(const s16x8*)(wrow_ + 16 * WSTR);                     \
        s16x8 b2_ = *(const s16x8*)(wrow_ + 32 * WSTR);                     \
        s16x8 b3_ = *(const s16x8*)(wrow_ + 48 * WSTR);                     \
        acc0 = __builtin_amdgcn_mfma_f32_16x16x32_bf16(b0_, af, acc0,0,0,0);\
        acc1 = __builtin_amdgcn_mfma_f32_16x16x32_bf16(b1_, af, acc1,0,0,0);\
        acc2 = __builtin_amdgcn_mfma_f32_16x16x32_bf16(b2_, af, acc2,0,0,0);\
        acc3 = __builtin_amdgcn_mfma_f32_16x16x32_bf16(b3_, af, acc3,0,0,0);\
    }                                                                       \
    const size_t Pq_ = (size_t)(ci_) * CHUNK + pl;                          \
    const bool zp_ = ((Pq_ & (NN - 1)) == (NN - 1));                        \
    float* orow_ = out + Pq_ * OO + fg * 4;                                 \
    _Pragma("unroll")                                                       \
    for (int ot_ = 0; ot_ < 4; ++ot_) {                                     \
        const f32x4 av_ = (ot_==0)?acc0:(ot_==1)?acc1:(ot_==2)?acc2:acc3;   \
        const f32x4 bv_ = *(const f32x4*)&BL[ot_ * 16 + fg * 4];            \
        f32x4 rr_;                                                          \
        _Pragma("unroll")                                                   \
        for (int j_ = 0; j_ < 4; ++j_)                                      \
            rr_[j_] = zp_ ? 0.f : elu1(av_[j_] + bv_[j_]);                  \
        *(f32x4*)(orow_ + ot_ * 16) = rr_;                                  \
    }                                                                       \
}

__global__ __launch_bounds__(THREADS, 2) void paiconv_pipe(
    const unsigned short* __restrict__ xbf,
    const int* __restrict__ nbr,
    const unsigned short* __restrict__ recA,
    const unsigned short* __restrict__ recB,
    const float* __restrict__ W,
    const float* __restrict__ bias,
    float* __restrict__ out)
{
    __shared__ short Wl[OO * WSTR];     // 37888 B
    __shared__ float BL[OO];

    const int tid = threadIdx.x;

    for (int e = tid; e < OO * DD / 4; e += THREADS) {
        int o = e / 72;
        int d4 = (e - o * 72) * 4;
        const f32x4 wv = *(const f32x4*)(W + o * DD + d4);
        s16x4 p;
        p.x = f2bf(wv.x); p.y = f2bf(wv.y); p.z = f2bf(wv.z); p.w = f2bf(wv.w);
        *(s16x4*)(&Wl[o * WSTR + d4]) = p;
    }
    if (tid < OO) BL[tid] = bias[tid];
    __syncthreads();                    // only barrier

    const int lane = tid & 63;
    const int wid  = tid >> 6;
    const int l15  = lane & 15;
    const int fg   = lane >> 4;
    const int fo   = fg * 8;
    const int pl   = wid * 16 + l15;

    // round-invariant vertex -> adjacency loaded ONCE (45 regs)
    const int n0 = blockIdx.x * CHUNK + pl;
    u32x4 adjP[KK];
    {
        const unsigned short* ra = recA + (size_t)n0 * RA_STRIDE;
        #pragma unroll
        for (int t = 0; t < KK; ++t) adjP[t] = *(const u32x4*)(ra + t * 8);
    }
    float rbf[KK];
    {
        const unsigned short* rbp = recB + (size_t)n0 * RB_STRIDE;
        #pragma unroll
        for (int t = 0; t < KK; ++t) rbf[t] = bf1(rbp[t]);
    }

    int nbrA[KK], nbrB[KK];
    u32x4 gpA[KK], gpB[KK];

    LOADNBR(nbrA, blockIdx.x);
    LOADNBR(nbrB, blockIdx.x + NBLOCKS);
    GATHER(gpA, nbrA, blockIdx.x);      // prologue: stalls once on nbrA

    #pragma unroll 1
    for (int rp = 0; rp < ROUNDS / 2; ++rp) {
        const int ciA = blockIdx.x + (2 * rp) * NBLOCKS;
        const int ciB = ciA + NBLOCKS;
        GATHER(gpB, nbrB, ciB);                       // in flight over COMPUTE(A)
        if (rp < ROUNDS / 2 - 1) LOADNBR(nbrA, ciA + 2 * NBLOCKS);
        COMPUTE(gpA, ciA);
        if (rp < ROUNDS / 2 - 1) {
            GATHER(gpA, nbrA, ciA + 2 * NBLOCKS);     // in flight over COMPUTE(B)
            LOADNBR(nbrB, ciB + 2 * NBLOCKS);
        }
        COMPUTE(gpB, ciB);
    }
}

// =============== fallback (no-ws) kernel: R8 f32 path ====================
__global__ __launch_bounds__(THREADS, 2) void paiconv_fb(
    const float* __restrict__ x,
    const int* __restrict__ nbr,
    const float* __restrict__ v,
    const float* __restrict__ aw,
    const float* __restrict__ W,
    const float* __restrict__ bias,
    float* __restrict__ out)
{
    __shared__ short Wl[OO * WSTR];
    __shared__ float BL[OO];
    const int tid = threadIdx.x;
    for (int e = tid; e < OO * DD / 4; e += THREADS) {
        int o = e / 72;
        int d4 = (e - o * 72) * 4;
        const f32x4 wv = *(const f32x4*)(W + o * DD + d4);
        s16x4 p;
        p.x = f2bf(wv.x); p.y = f2bf(wv.y); p.z = f2bf(wv.z); p.w = f2bf(wv.w);
        *(s16x4*)(&Wl[o * WSTR + d4]) = p;
    }
    if (tid < OO) BL[tid] = bias[tid];
    __syncthreads();

    const int lane = tid & 63;
    const int wid  = tid >> 6;
    const int l15  = lane & 15;
    const int fg   = lane >> 4;
    const int fo   = fg * 8;
    const int pl   = wid * 16 + l15;

    for (int ci = blockIdx.x; ci < NCHUNKS; ci += NBLOCKS) {
        const int cbase = ci * CHUNK;
        const int P = cbase + pl;
        const int n = P & (NN - 1);
        const int b = P >> NLOG;
        const int* nip = nbr + (size_t)P * KK;
        const float* xb = x + (((size_t)b) << NLOG) * FF;

        f32x2 G2[KK][4];
        #pragma unroll
        for (int k = 0; k < KK; ++k) {
            const float* src = xb + (size_t)nip[k] * FF + fo;
            const f32x4 g0 = *(const f32x4*)(src);
            const f32x4 g1 = *(const f32x4*)(src + 4);
            G2[k][0] = f32x2{g0.x, g0.y};
            G2[k][1] = f32x2{g0.z, g0.w};
            G2[k][2] = f32x2{g1.x, g1.y};
            G2[k][3] = f32x2{g1.z, g1.w};
        }
        float vr[8];
        #pragma unroll
        for (int si = 0; si < 8; ++si) vr[si] = v[n * 8 + si];

        f32x4 acc0 = {0,0,0,0}, acc1 = {0,0,0,0}, acc2 = {0,0,0,0}, acc3 = {0,0,0,0};
        #pragma unroll
        for (int t = 0; t < KK; ++t) {
            float a[KK];
            #pragma unroll
            for (int k = 0; k < KK; ++k) {
                float s = 0.f;
                #pragma unroll
                for (int si = 0; si < 8; ++si)
                    s += vr[si] * aw[si * 81 + k * 9 + t];
                a[k] = s;
            }
            f32x2 xn2[4] = {{0,0},{0,0},{0,0},{0,0}};
            #pragma unroll
            for (int k = 0; k < KK; ++k) {
                const f32x2 ak = {a[k], a[k]};
                #pragma unroll
                for (int i = 0; i < 4; ++i) xn2[i] += G2[k][i] * ak;
            }
            s16x8 af;
            #pragma unroll
            for (int i = 0; i < 4; ++i) {
                af[2*i]   = f2bf(elu1(xn2[i].x));
                af[2*i+1] = f2bf(elu1(xn2[i].y));
            }
            const short* wrow = &Wl[l15 * WSTR + t * FF + fo];
            s16x8 b0 = *(const s16x8*)(wrow);
            s16x8 b1 = *(const s16x8*)(wrow + 16 * WSTR);
            s16x8 b2 = *(const s16x8*)(wrow + 32 * WSTR);
            s16x8 b3 = *(const s16x8*)(wrow + 48 * WSTR);
            acc0 = __builtin_amdgcn_mfma_f32_16x16x32_bf16(b0, af, acc0, 0, 0, 0);
            acc1 = __builtin_amdgcn_mfma_f32_16x16x32_bf16(b1, af, acc1, 0, 0, 0);
            acc2 = __builtin_amdgcn_mfma_f32_16x16x32_bf16(b2, af, acc2, 0, 0, 0);
            acc3 = __builtin_amdgcn_mfma_f32_16x16x32_bf16(b3, af, acc3, 0, 0, 0);
        }
        const bool zero_pt = ((P & (NN - 1)) == (NN - 1));
        float* orow = out + (size_t)P * OO + fg * 4;
        #pragma unroll
        for (int ot = 0; ot < 4; ++ot) {
            const f32x4 a = (ot == 0) ? acc0 : (ot == 1) ? acc1 : (ot == 2) ? acc2 : acc3;
            const f32x4 bv = *(const f32x4*)&BL[ot * 16 + fg * 4];
            f32x4 r;
            #pragma unroll
            for (int j = 0; j < 4; ++j)
                r[j] = zero_pt ? 0.f : elu1(a[j] + bv[j]);
            *(f32x4*)(orow + ot * 16) = r;
        }
    }
}

extern "C" void kernel_launch(void* const* d_in, const int* in_sizes, int n_in,
                              void* d_out, int out_size, void* d_ws, size_t ws_size,
                              hipStream_t stream) {
    const float* x    = (const float*)d_in[0];
    // d_in[1] = t_vertex (unused in forward)
    const int*   nbr  = (const int*)d_in[2];
    const float* v    = (const float*)d_in[3];
    const float* aw   = (const float*)d_in[4];
    const float* W    = (const float*)d_in[5];
    const float* bias = (const float*)d_in[6];
    float* out = (float*)d_out;

    const size_t xbf_bytes = (size_t)TOTALP * FF * 2;     // 33,554,432
    const size_t ra_bytes  = (size_t)NN * RA_STRIDE * 2;  //  9,437,184
    const size_t rb_bytes  = (size_t)NN * RB_STRIDE * 2;  //  1,310,720
    const size_t need = xbf_bytes + ra_bytes + rb_bytes;  // ~44.3 MB

    if (ws_size >= need) {
        unsigned short* xbf  = (unsigned short*)d_ws;
        unsigned short* recA = (unsigned short*)((char*)d_ws + xbf_bytes);
        unsigned short* recB = (unsigned short*)((char*)d_ws + xbf_bytes + ra_bytes);
        hipLaunchKernelGGL(xcvt, dim3((TOTALP * FF / 8) / THREADS), dim3(THREADS),
                           0, stream, x, xbf);
        hipLaunchKernelGGL(adjcvt, dim3((NN * KK) / THREADS), dim3(THREADS),
                           0, stream, v, aw, recA, recB);
        hipLaunchKernelGGL(paiconv_pipe, dim3(NBLOCKS), dim3(THREADS), 0, stream,
                           xbf, nbr, recA, recB, W, bias, out);
    } else {
        hipLaunchKernelGGL(paiconv_fb, dim3(NBLOCKS), dim3(THREADS), 0, stream,
                           x, nbr, v, aw, W, bias, out);
    }
}

// Round 10
// 404.611 us; speedup vs baseline: 1.4186x; 1.4186x over previous
//
#include <hip/hip_runtime.h>
#include <hip/hip_bf16.h>

#define NLOG 16
#define NN 65536
#define KK 9
#define FF 32
#define OO 64
#define DD 288            // K*F
#define WSTR 296          // padded W row stride (shorts)
#define CHUNK 64          // points per block-chunk
#define THREADS 256
#define NBLOCKS 1024
#define TOTALP (8 * NN)           // 524288
#define NCHUNKS (TOTALP / CHUNK)  // 8192
#define RA_STRIDE 72              // shorts/point: 9 t-rows x 8 bf16 (16B rows)
#define RB_STRIDE 10              // shorts/point: k=8 column over t, +1 pad
#define AJW 88                    // LDS adjacency stride (shorts): 72 recA + 9 recB + 7 pad

typedef float f32x4 __attribute__((ext_vector_type(4)));
typedef float f32x2 __attribute__((ext_vector_type(2)));
typedef unsigned int u32x4 __attribute__((ext_vector_type(4)));
typedef short s16x8 __attribute__((ext_vector_type(8)));
typedef short s16x4 __attribute__((ext_vector_type(4)));

static __device__ __forceinline__ short f2bf(float f) {
    union { __hip_bfloat16 h; short s; } u;
    u.h = __float2bfloat16(f);
    return u.s;
}

// exact bf16->f32
static __device__ __forceinline__ void bf2f2(unsigned int p, float& lo, float& hi) {
    union { unsigned int u; float f; } a, b;
    a.u = p << 16;
    b.u = p & 0xFFFF0000u;
    lo = a.f; hi = b.f;
}
static __device__ __forceinline__ float bf1(unsigned short s) {
    union { unsigned int u; float f; } a;
    a.u = ((unsigned int)s) << 16;
    return a.f;
}

static __device__ __forceinline__ float elu1(float x) {
    float e = __expf(fminf(x, 0.f)) - 1.f;
    return x > 0.f ? x : e;
}

// ---- pre-kernel 1: x (f32) -> xbf (bf16), same layout ----
__global__ __launch_bounds__(THREADS) void xcvt(
    const float* __restrict__ x, unsigned short* __restrict__ xbf)
{
    const size_t i = ((size_t)blockIdx.x * THREADS + threadIdx.x) * 8;
    const f32x4 a = *(const f32x4*)(x + i);
    const f32x4 b = *(const f32x4*)(x + i + 4);
    s16x8 p;
    p[0] = f2bf(a.x); p[1] = f2bf(a.y); p[2] = f2bf(a.z); p[3] = f2bf(a.w);
    p[4] = f2bf(b.x); p[5] = f2bf(b.y); p[6] = f2bf(b.z); p[7] = f2bf(b.w);
    *(s16x8*)(xbf + i) = p;
}

// ---- pre-kernel 2: adjacency -> packed bf16 (recA: k=0..7, recB: k=8) ----
__global__ __launch_bounds__(THREADS) void adjcvt(
    const float* __restrict__ v, const float* __restrict__ aw,
    unsigned short* __restrict__ recA, unsigned short* __restrict__ recB)
{
    const int e = blockIdx.x * THREADS + threadIdx.x;   // over NN*KK exact
    const int n = e / KK;
    const int t = e - n * KK;
    const float* vr = v + n * 8;
    short o[8];
    float s8 = 0.f;
    #pragma unroll
    for (int k = 0; k < KK; ++k) {
        float s = 0.f;
        #pragma unroll
        for (int si = 0; si < 8; ++si)
            s += vr[si] * aw[si * 81 + k * 9 + t];
        if (k < 8) o[k] = f2bf(s); else s8 = s;
    }
    *(s16x8*)(recA + (size_t)n * RA_STRIDE + t * 8) = *(s16x8*)o;
    recB[(size_t)n * RB_STRIDE + t] = (unsigned short)f2bf(s8);
    if (t == 0) recB[(size_t)n * RB_STRIDE + 9] = 0;
}

// =========================== main kernel (PRE) ===========================
// Byte-floor design (R10):
//  * bf16 x gather from ws: 4.2 MB/batch, 2 rows per 128B line -> per-XCD
//    compulsory fill floor ~240 MB (vs 362 f32). Full 64B row consumed by
//    the 4 fg-lanes (u32x4 each) - no intra-row waste.
//  * Adjacency staged ONCE into LDS per block (vertex range bid*64..+64 is
//    identical across all 8 batch-rounds): kills the 86 MB adj stream AND
//    its L2 pollution (R4/R7's failure cause), plus its per-chunk latency.
//  * Unpinned grid-stride (R7: pinning thrashes per-XCD L2). No nt (R5).
//    No reg-pipelining (R9: spills). Swapped MFMA + f32x4 stores (R8).
//  * LDS 49.4 KB -> 3 blocks/CU (12 waves). __launch_bounds__(256,2): ",4"
//    caps VGPR below live G2[9][4] -> spills (R2).
__global__ __launch_bounds__(THREADS, 2) void paiconv_main(
    const unsigned short* __restrict__ xbf,
    const int* __restrict__ nbr,
    const unsigned short* __restrict__ recA,
    const unsigned short* __restrict__ recB,
    const float* __restrict__ W,
    const float* __restrict__ bias,
    float* __restrict__ out)
{
    __shared__ short Wl[OO * WSTR];          // 37888 B
    __shared__ unsigned short AJ[CHUNK * AJW]; // 11264 B
    __shared__ float BL[OO];                 // 256 B  -> 49408 B total

    const int tid = threadIdx.x;
    const int vbase = blockIdx.x * CHUNK;    // block's vertex range (round-invariant)

    // stage W (fp32 global -> bf16 LDS), once per block
    for (int e = tid; e < OO * DD / 4; e += THREADS) {
        int o = e / 72;
        int d4 = (e - o * 72) * 4;
        const f32x4 wv = *(const f32x4*)(W + o * DD + d4);
        s16x4 p;
        p.x = f2bf(wv.x); p.y = f2bf(wv.y); p.z = f2bf(wv.z); p.w = f2bf(wv.w);
        *(s16x4*)(&Wl[o * WSTR + d4]) = p;
    }
    // stage adjacency for the block's 64 vertices, once per kernel
    for (int e = tid; e < CHUNK * KK; e += THREADS) {
        const int p = e / KK;
        const int t = e - p * KK;
        const u32x4 r = *(const u32x4*)(recA + (size_t)(vbase + p) * RA_STRIDE + t * 8);
        *(u32x4*)(&AJ[p * AJW + t * 8]) = r;
    }
    if (tid < CHUNK) {
        #pragma unroll
        for (int t = 0; t < KK; ++t)
            AJ[tid * AJW + RA_STRIDE + t] = recB[(size_t)(vbase + tid) * RB_STRIDE + t];
    }
    if (tid < OO) BL[tid] = bias[tid];
    __syncthreads();                    // only barrier in the kernel

    const int lane = tid & 63;
    const int wid  = tid >> 6;
    const int l15  = lane & 15;       // point within 16-tile (B-col) / W-row (A)
    const int fg   = lane >> 4;       // octet group
    const int fo   = fg * 8;          // f offset (shorts) of this lane's octet
    const int pl   = wid * 16 + l15;  // point within chunk

    for (int ci = blockIdx.x; ci < NCHUNKS; ci += NBLOCKS) {
        const size_t P = (size_t)ci * CHUNK + pl;
        const int b = (int)(P >> NLOG);
        const int* nip = nbr + P * KK;
        const unsigned short* xb = xbf + ((((size_t)b) << NLOG) * FF) + fo;

        // gather neighbor features (bf16) and unpack: G2[k][i] = {f(2i), f(2i+1)}
        f32x2 G2[KK][4];
        #pragma unroll
        for (int k = 0; k < KK; ++k) {
            const u32x4 g = *(const u32x4*)(xb + (size_t)nip[k] * FF);
            float l0,h0,l1,h1,l2,h2,l3,h3;
            bf2f2(g.x, l0, h0);
            bf2f2(g.y, l1, h1);
            bf2f2(g.z, l2, h2);
            bf2f2(g.w, l3, h3);
            G2[k][0] = f32x2{l0, h0};
            G2[k][1] = f32x2{l1, h1};
            G2[k][2] = f32x2{l2, h2};
            G2[k][3] = f32x2{l3, h3};
        }

        f32x4 acc0 = {0,0,0,0}, acc1 = {0,0,0,0}, acc2 = {0,0,0,0}, acc3 = {0,0,0,0};

        #pragma unroll
        for (int t = 0; t < KK; ++t) {
            float a[KK];
            {
                const u32x4 qv = *(const u32x4*)(&AJ[pl * AJW + t * 8]);  // LDS, 16B
                bf2f2(qv.x, a[0], a[1]);
                bf2f2(qv.y, a[2], a[3]);
                bf2f2(qv.z, a[4], a[5]);
                bf2f2(qv.w, a[6], a[7]);
                a[8] = bf1(AJ[pl * AJW + RA_STRIDE + t]);
            }

            f32x2 xn2[4] = {{0,0},{0,0},{0,0},{0,0}};
            #pragma unroll
            for (int k = 0; k < KK; ++k) {
                const f32x2 ak = {a[k], a[k]};
                #pragma unroll
                for (int i = 0; i < 4; ++i) xn2[i] += G2[k][i] * ak;
            }
            s16x8 af;
            #pragma unroll
            for (int i = 0; i < 4; ++i) {
                af[2*i]   = f2bf(elu1(xn2[i].x));
                af[2*i+1] = f2bf(elu1(xn2[i].y));
            }

            const short* wrow = &Wl[l15 * WSTR + t * FF + fo];
            s16x8 b0 = *(const s16x8*)(wrow);
            s16x8 b1 = *(const s16x8*)(wrow + 16 * WSTR);
            s16x8 b2 = *(const s16x8*)(wrow + 32 * WSTR);
            s16x8 b3 = *(const s16x8*)(wrow + 48 * WSTR);
            // swapped: A = W tile (row=o within 16-group), B = xn (col=point)
            acc0 = __builtin_amdgcn_mfma_f32_16x16x32_bf16(b0, af, acc0, 0, 0, 0);
            acc1 = __builtin_amdgcn_mfma_f32_16x16x32_bf16(b1, af, acc1, 0, 0, 0);
            acc2 = __builtin_amdgcn_mfma_f32_16x16x32_bf16(b2, af, acc2, 0, 0, 0);
            acc3 = __builtin_amdgcn_mfma_f32_16x16x32_bf16(b3, af, acc3, 0, 0, 0);
        }

        // epilogue: C col(l15)=point P, row(fg*4+reg)=o within 16-group ot.
        const bool zero_pt = ((P & (NN - 1)) == (NN - 1));
        float* orow = out + P * OO + fg * 4;
        #pragma unroll
        for (int ot = 0; ot < 4; ++ot) {
            const f32x4 a = (ot == 0) ? acc0 : (ot == 1) ? acc1 : (ot == 2) ? acc2 : acc3;
            const f32x4 bv = *(const f32x4*)&BL[ot * 16 + fg * 4];
            f32x4 r;
            #pragma unroll
            for (int j = 0; j < 4; ++j)
                r[j] = zero_pt ? 0.f : elu1(a[j] + bv[j]);
            *(f32x4*)(orow + ot * 16) = r;
        }
    }
}

// =============== fallback (no-ws) kernel: R8 f32 path ====================
__global__ __launch_bounds__(THREADS, 2) void paiconv_fb(
    const float* __restrict__ x,
    const int* __restrict__ nbr,
    const float* __restrict__ v,
    const float* __restrict__ aw,
    const float* __restrict__ W,
    const float* __restrict__ bias,
    float* __restrict__ out)
{
    __shared__ short Wl[OO * WSTR];
    __shared__ float BL[OO];
    const int tid = threadIdx.x;
    for (int e = tid; e < OO * DD / 4; e += THREADS) {
        int o = e / 72;
        int d4 = (e - o * 72) * 4;
        const f32x4 wv = *(const f32x4*)(W + o * DD + d4);
        s16x4 p;
        p.x = f2bf(wv.x); p.y = f2bf(wv.y); p.z = f2bf(wv.z); p.w = f2bf(wv.w);
        *(s16x4*)(&Wl[o * WSTR + d4]) = p;
    }
    if (tid < OO) BL[tid] = bias[tid];
    __syncthreads();

    const int lane = tid & 63;
    const int wid  = tid >> 6;
    const int l15  = lane & 15;
    const int fg   = lane >> 4;
    const int fo   = fg * 8;
    const int pl   = wid * 16 + l15;

    for (int ci = blockIdx.x; ci < NCHUNKS; ci += NBLOCKS) {
        const int cbase = ci * CHUNK;
        const int P = cbase + pl;
        const int n = P & (NN - 1);
        const int b = P >> NLOG;
        const int* nip = nbr + (size_t)P * KK;
        const float* xb = x + (((size_t)b) << NLOG) * FF;

        f32x2 G2[KK][4];
        #pragma unroll
        for (int k = 0; k < KK; ++k) {
            const float* src = xb + (size_t)nip[k] * FF + fo;
            const f32x4 g0 = *(const f32x4*)(src);
            const f32x4 g1 = *(const f32x4*)(src + 4);
            G2[k][0] = f32x2{g0.x, g0.y};
            G2[k][1] = f32x2{g0.z, g0.w};
            G2[k][2] = f32x2{g1.x, g1.y};
            G2[k][3] = f32x2{g1.z, g1.w};
        }
        float vr[8];
        #pragma unroll
        for (int si = 0; si < 8; ++si) vr[si] = v[n * 8 + si];

        f32x4 acc0 = {0,0,0,0}, acc1 = {0,0,0,0}, acc2 = {0,0,0,0}, acc3 = {0,0,0,0};
        #pragma unroll
        for (int t = 0; t < KK; ++t) {
            float a[KK];
            #pragma unroll
            for (int k = 0; k < KK; ++k) {
                float s = 0.f;
                #pragma unroll
                for (int si = 0; si < 8; ++si)
                    s += vr[si] * aw[si * 81 + k * 9 + t];
                a[k] = s;
            }
            f32x2 xn2[4] = {{0,0},{0,0},{0,0},{0,0}};
            #pragma unroll
            for (int k = 0; k < KK; ++k) {
                const f32x2 ak = {a[k], a[k]};
                #pragma unroll
                for (int i = 0; i < 4; ++i) xn2[i] += G2[k][i] * ak;
            }
            s16x8 af;
            #pragma unroll
            for (int i = 0; i < 4; ++i) {
                af[2*i]   = f2bf(elu1(xn2[i].x));
                af[2*i+1] = f2bf(elu1(xn2[i].y));
            }
            const short* wrow = &Wl[l15 * WSTR + t * FF + fo];
            s16x8 b0 = *(const s16x8*)(wrow);
            s16x8 b1 = *(const s16x8*)(wrow + 16 * WSTR);
            s16x8 b2 = *(const s16x8*)(wrow + 32 * WSTR);
            s16x8 b3 = *(const s16x8*)(wrow + 48 * WSTR);
            acc0 = __builtin_amdgcn_mfma_f32_16x16x32_bf16(b0, af, acc0, 0, 0, 0);
            acc1 = __builtin_amdgcn_mfma_f32_16x16x32_bf16(b1, af, acc1, 0, 0, 0);
            acc2 = __builtin_amdgcn_mfma_f32_16x16x32_bf16(b2, af, acc2, 0, 0, 0);
            acc3 = __builtin_amdgcn_mfma_f32_16x16x32_bf16(b3, af, acc3, 0, 0, 0);
        }
        const bool zero_pt = ((P & (NN - 1)) == (NN - 1));
        float* orow = out + (size_t)P * OO + fg * 4;
        #pragma unroll
        for (int ot = 0; ot < 4; ++ot) {
            const f32x4 a = (ot == 0) ? acc0 : (ot == 1) ? acc1 : (ot == 2) ? acc2 : acc3;
            const f32x4 bv = *(const f32x4*)&BL[ot * 16 + fg * 4];
            f32x4 r;
            #pragma unroll
            for (int j = 0; j < 4; ++j)
                r[j] = zero_pt ? 0.f : elu1(a[j] + bv[j]);
            *(f32x4*)(orow + ot * 16) = r;
        }
    }
}

extern "C" void kernel_launch(void* const* d_in, const int* in_sizes, int n_in,
                              void* d_out, int out_size, void* d_ws, size_t ws_size,
                              hipStream_t stream) {
    const float* x    = (const float*)d_in[0];
    // d_in[1] = t_vertex (unused in forward)
    const int*   nbr  = (const int*)d_in[2];
    const float* v    = (const float*)d_in[3];
    const float* aw   = (const float*)d_in[4];
    const float* W    = (const float*)d_in[5];
    const float* bias = (const float*)d_in[6];
    float* out = (float*)d_out;

    const size_t xbf_bytes = (size_t)TOTALP * FF * 2;     // 33,554,432
    const size_t ra_bytes  = (size_t)NN * RA_STRIDE * 2;  //  9,437,184
    const size_t rb_bytes  = (size_t)NN * RB_STRIDE * 2;  //  1,310,720
    const size_t need = xbf_bytes + ra_bytes + rb_bytes;  // ~44.3 MB

    if (ws_size >= need) {
        unsigned short* xbf  = (unsigned short*)d_ws;
        unsigned short* recA = (unsigned short*)((char*)d_ws + xbf_bytes);
        unsigned short* recB = (unsigned short*)((char*)d_ws + xbf_bytes + ra_bytes);
        hipLaunchKernelGGL(xcvt, dim3((TOTALP * FF / 8) / THREADS), dim3(THREADS),
                           0, stream, x, xbf);
        hipLaunchKernelGGL(adjcvt, dim3((NN * KK) / THREADS), dim3(THREADS),
                           0, stream, v, aw, recA, recB);
        hipLaunchKernelGGL(paiconv_main, dim3(NBLOCKS), dim3(THREADS), 0, stream,
                           xbf, nbr, recA, recB, W, bias, out);
    } else {
        hipLaunchKernelGGL(paiconv_fb, dim3(NBLOCKS), dim3(THREADS), 0, stream,
                           x, nbr, v, aw, W, bias, out);
    }
}

// Round 11
// 239.712 us; speedup vs baseline: 2.3944x; 1.6879x over previous
//
#include <hip/hip_runtime.h>
#include <hip/hip_bf16.h>

#define NLOG 16
#define NN 65536
#define KK 9
#define FF 32
#define OO 64
#define DD 288            // K*F
#define WSTR 296          // padded W row stride (shorts)
#define CHUNK 64          // points per block-chunk
#define THREADS 256
#define NBLOCKS 1024
#define TOTALP (8 * NN)           // 524288
#define NCHUNKS (TOTALP / CHUNK)  // 8192
#define RA_STRIDE 72              // shorts/point: 9 t-rows x 8 bf16 (16B rows)
#define RB_STRIDE 10              // shorts/point: k=8 column over t, +1 pad

typedef float f32x4 __attribute__((ext_vector_type(4)));
typedef float f32x2 __attribute__((ext_vector_type(2)));
typedef unsigned int u32x4 __attribute__((ext_vector_type(4)));
typedef short s16x8 __attribute__((ext_vector_type(8)));
typedef short s16x4 __attribute__((ext_vector_type(4)));

static __device__ __forceinline__ short f2bf(float f) {
    union { __hip_bfloat16 h; short s; } u;
    u.h = __float2bfloat16(f);
    return u.s;
}

// exact bf16->f32
static __device__ __forceinline__ void bf2f2(unsigned int p, float& lo, float& hi) {
    union { unsigned int u; float f; } a, b;
    a.u = p << 16;
    b.u = p & 0xFFFF0000u;
    lo = a.f; hi = b.f;
}
static __device__ __forceinline__ float bf1(unsigned short s) {
    union { unsigned int u; float f; } a;
    a.u = ((unsigned int)s) << 16;
    return a.f;
}

static __device__ __forceinline__ float elu1(float x) {
    float e = __expf(fminf(x, 0.f)) - 1.f;
    return x > 0.f ? x : e;
}

// ---- pre-kernel 1: x (f32) -> xbf (bf16), same layout ----
__global__ __launch_bounds__(THREADS) void xcvt(
    const float* __restrict__ x, unsigned short* __restrict__ xbf)
{
    const size_t i = ((size_t)blockIdx.x * THREADS + threadIdx.x) * 8;
    const f32x4 a = *(const f32x4*)(x + i);
    const f32x4 b = *(const f32x4*)(x + i + 4);
    s16x8 p;
    p[0] = f2bf(a.x); p[1] = f2bf(a.y); p[2] = f2bf(a.z); p[3] = f2bf(a.w);
    p[4] = f2bf(b.x); p[5] = f2bf(b.y); p[6] = f2bf(b.z); p[7] = f2bf(b.w);
    *(s16x8*)(xbf + i) = p;
}

// ---- pre-kernel 2: adjacency -> packed bf16 (recA: k=0..7, recB: k=8) ----
__global__ __launch_bounds__(THREADS) void adjcvt(
    const float* __restrict__ v, const float* __restrict__ aw,
    unsigned short* __restrict__ recA, unsigned short* __restrict__ recB)
{
    const int e = blockIdx.x * THREADS + threadIdx.x;   // over NN*KK exact
    const int n = e / KK;
    const int t = e - n * KK;
    const float* vr = v + n * 8;
    short o[8];
    float s8 = 0.f;
    #pragma unroll
    for (int k = 0; k < KK; ++k) {
        float s = 0.f;
        #pragma unroll
        for (int si = 0; si < 8; ++si)
            s += vr[si] * aw[si * 81 + k * 9 + t];
        if (k < 8) o[k] = f2bf(s); else s8 = s;
    }
    *(s16x8*)(recA + (size_t)n * RA_STRIDE + t * 8) = *(s16x8*)o;
    recB[(size_t)n * RB_STRIDE + t] = (unsigned short)f2bf(s8);
    if (t == 0) recB[(size_t)n * RB_STRIDE + 9] = 0;
}

// ---- main kernel: R8 structure EXACTLY, single diff = bf16 x gather ----
// Ledger (hard-won):
//  * R8 (f32 gather, global bf16 adj) = 230.7us timed, FETCH 421, WRITE 164,
//    VGPR 128 no spill. Best so far; R1/R3 also ~231.
//  * Effective byte-rate ~2.5 TB/s on gather-dominated mixes (R3/R6/R8) ->
//    this round halves the gather line-set via bf16 x (slice 4.2MB,
//    ~4.7x XCD-duplication measured) -> predicted FETCH ~280MB.
//  * Every structure richer than R8 spilled (R2: bounds-4; R9: reg pipeline;
//    R10: +AJ-LDS +unpack transients). This round's diff REDUCES pressure
//    (one u32x4 load per row instead of two f32x4).
//  * Unpinned grid-stride (R7: pinning thrashes 4MB per-XCD L2). No nt (R5).
//    Swapped MFMA + f32x4 stores (R8). __launch_bounds__(256,2) NOT 4 (R2).
template<bool PRE>
__global__ __launch_bounds__(THREADS, 2) void paiconv_main(
    const float* __restrict__ x,
    const unsigned short* __restrict__ xbf,
    const int* __restrict__ nbr,
    const float* __restrict__ v,
    const float* __restrict__ aw,
    const unsigned short* __restrict__ recA,
    const unsigned short* __restrict__ recB,
    const float* __restrict__ W,
    const float* __restrict__ bias,
    float* __restrict__ out)
{
    __shared__ short Wl[OO * WSTR];     // 37888 B
    __shared__ float BL[OO];            // -> 4 blocks/CU

    const int tid = threadIdx.x;

    // stage W (fp32 global -> bf16 LDS), once per block
    for (int e = tid; e < OO * DD / 4; e += THREADS) {
        int o = e / 72;
        int d4 = (e - o * 72) * 4;
        const f32x4 wv = *(const f32x4*)(W + o * DD + d4);
        s16x4 p;
        p.x = f2bf(wv.x); p.y = f2bf(wv.y); p.z = f2bf(wv.z); p.w = f2bf(wv.w);
        *(s16x4*)(&Wl[o * WSTR + d4]) = p;
    }
    if (tid < OO) BL[tid] = bias[tid];
    __syncthreads();                    // only barrier in the kernel

    const int lane = tid & 63;
    const int wid  = tid >> 6;
    const int l15  = lane & 15;       // point within 16-tile (B-col) / W-row (A)
    const int fg   = lane >> 4;       // octet group
    const int fo   = fg * 8;          // f offset of this lane's octet
    const int pl   = wid * 16 + l15;  // point within chunk

    for (int ci = blockIdx.x; ci < NCHUNKS; ci += NBLOCKS) {
        const int cbase = ci * CHUNK;
        const int P = cbase + pl;
        const int n = P & (NN - 1);
        const int b = P >> NLOG;
        const int* nip = nbr + (size_t)P * KK;

        // gather neighbor features: G2[k][i] = {f(fo+2i), f(fo+2i+1)}
        f32x2 G2[KK][4];
        if (PRE) {
            const unsigned short* xb = xbf + (((size_t)b) << NLOG) * FF + fo;
            #pragma unroll
            for (int k = 0; k < KK; ++k) {
                const u32x4 g = *(const u32x4*)(xb + (size_t)nip[k] * FF);
                float l0,h0,l1,h1,l2,h2,l3,h3;
                bf2f2(g.x, l0, h0);
                bf2f2(g.y, l1, h1);
                bf2f2(g.z, l2, h2);
                bf2f2(g.w, l3, h3);
                G2[k][0] = f32x2{l0, h0};
                G2[k][1] = f32x2{l1, h1};
                G2[k][2] = f32x2{l2, h2};
                G2[k][3] = f32x2{l3, h3};
            }
        } else {
            const float* xb = x + (((size_t)b) << NLOG) * FF;
            #pragma unroll
            for (int k = 0; k < KK; ++k) {
                const float* src = xb + (size_t)nip[k] * FF + fo;
                const f32x4 g0 = *(const f32x4*)(src);
                const f32x4 g1 = *(const f32x4*)(src + 4);
                G2[k][0] = f32x2{g0.x, g0.y};
                G2[k][1] = f32x2{g0.z, g0.w};
                G2[k][2] = f32x2{g1.x, g1.y};
                G2[k][3] = f32x2{g1.z, g1.w};
            }
        }

        float vr[8];
        if (!PRE) {
            #pragma unroll
            for (int si = 0; si < 8; ++si) vr[si] = v[n * 8 + si];
        }

        f32x4 acc0 = {0,0,0,0}, acc1 = {0,0,0,0}, acc2 = {0,0,0,0}, acc3 = {0,0,0,0};

        const unsigned short* ra = recA + (size_t)n * RA_STRIDE;
        const unsigned short* rb = recB + (size_t)n * RB_STRIDE;

        #pragma unroll
        for (int t = 0; t < KK; ++t) {
            float a[KK];
            if (PRE) {
                const u32x4 qv = *(const u32x4*)(ra + t * 8);   // 16B aligned
                bf2f2(qv.x, a[0], a[1]);
                bf2f2(qv.y, a[2], a[3]);
                bf2f2(qv.z, a[4], a[5]);
                bf2f2(qv.w, a[6], a[7]);
                a[8] = bf1(rb[t]);
            } else {
                #pragma unroll
                for (int k = 0; k < KK; ++k) {
                    float s = 0.f;
                    #pragma unroll
                    for (int si = 0; si < 8; ++si)
                        s += vr[si] * aw[si * 81 + k * 9 + t];
                    a[k] = s;
                }
            }

            f32x2 xn2[4] = {{0,0},{0,0},{0,0},{0,0}};
            #pragma unroll
            for (int k = 0; k < KK; ++k) {
                const f32x2 ak = {a[k], a[k]};
                #pragma unroll
                for (int i = 0; i < 4; ++i) xn2[i] += G2[k][i] * ak;
            }
            s16x8 af;
            #pragma unroll
            for (int i = 0; i < 4; ++i) {
                af[2*i]   = f2bf(elu1(xn2[i].x));
                af[2*i+1] = f2bf(elu1(xn2[i].y));
            }

            const short* wrow = &Wl[l15 * WSTR + t * FF + fo];
            s16x8 b0 = *(const s16x8*)(wrow);
            s16x8 b1 = *(const s16x8*)(wrow + 16 * WSTR);
            s16x8 b2 = *(const s16x8*)(wrow + 32 * WSTR);
            s16x8 b3 = *(const s16x8*)(wrow + 48 * WSTR);
            // swapped: A = W tile (row=o within 16-group), B = xn (col=point)
            acc0 = __builtin_amdgcn_mfma_f32_16x16x32_bf16(b0, af, acc0, 0, 0, 0);
            acc1 = __builtin_amdgcn_mfma_f32_16x16x32_bf16(b1, af, acc1, 0, 0, 0);
            acc2 = __builtin_amdgcn_mfma_f32_16x16x32_bf16(b2, af, acc2, 0, 0, 0);
            acc3 = __builtin_amdgcn_mfma_f32_16x16x32_bf16(b3, af, acc3, 0, 0, 0);
        }

        // epilogue: C col(l15)=point P, row(fg*4+reg)=o within 16-group ot.
        const bool zero_pt = ((P & (NN - 1)) == (NN - 1));
        float* orow = out + (size_t)P * OO + fg * 4;
        #pragma unroll
        for (int ot = 0; ot < 4; ++ot) {
            const f32x4 a = (ot == 0) ? acc0 : (ot == 1) ? acc1 : (ot == 2) ? acc2 : acc3;
            const f32x4 bv = *(const f32x4*)&BL[ot * 16 + fg * 4];
            f32x4 r;
            #pragma unroll
            for (int j = 0; j < 4; ++j)
                r[j] = zero_pt ? 0.f : elu1(a[j] + bv[j]);
            *(f32x4*)(orow + ot * 16) = r;
        }
    }
}

extern "C" void kernel_launch(void* const* d_in, const int* in_sizes, int n_in,
                              void* d_out, int out_size, void* d_ws, size_t ws_size,
                              hipStream_t stream) {
    const float* x    = (const float*)d_in[0];
    // d_in[1] = t_vertex (unused in forward)
    const int*   nbr  = (const int*)d_in[2];
    const float* v    = (const float*)d_in[3];
    const float* aw   = (const float*)d_in[4];
    const float* W    = (const float*)d_in[5];
    const float* bias = (const float*)d_in[6];
    float* out = (float*)d_out;

    const size_t xbf_bytes = (size_t)TOTALP * FF * 2;     // 33,554,432
    const size_t ra_bytes  = (size_t)NN * RA_STRIDE * 2;  //  9,437,184
    const size_t rb_bytes  = (size_t)NN * RB_STRIDE * 2;  //  1,310,720
    const size_t need = xbf_bytes + ra_bytes + rb_bytes;  // ~44.3 MB

    if (ws_size >= need) {
        unsigned short* xbf  = (unsigned short*)d_ws;
        unsigned short* recA = (unsigned short*)((char*)d_ws + xbf_bytes);
        unsigned short* recB = (unsigned short*)((char*)d_ws + xbf_bytes + ra_bytes);
        hipLaunchKernelGGL(xcvt, dim3((TOTALP * FF / 8) / THREADS), dim3(THREADS),
                           0, stream, x, xbf);
        hipLaunchKernelGGL(adjcvt, dim3((NN * KK) / THREADS), dim3(THREADS),
                           0, stream, v, aw, recA, recB);
        hipLaunchKernelGGL((paiconv_main<true>), dim3(NBLOCKS), dim3(THREADS), 0, stream,
                           x, xbf, nbr, v, aw, recA, recB, W, bias, out);
    } else {
        hipLaunchKernelGGL((paiconv_main<false>), dim3(NBLOCKS), dim3(THREADS), 0, stream,
                           x, (const unsigned short*)nullptr, nbr, v, aw,
                           (const unsigned short*)nullptr, (const unsigned short*)nullptr,
                           W, bias, out);
    }
}

// Round 12
// 204.860 us; speedup vs baseline: 2.8018x; 1.1701x over previous
//
#include <hip/hip_runtime.h>
#include <hip/hip_bf16.h>

#define NLOG 16
#define NN 65536
#define KK 9
#define FF 32
#define OO 64
#define DD 288            // K*F
#define WSTR 296          // padded W row stride (shorts), fallback LDS path only
#define CHUNK 64          // points per block-chunk
#define THREADS 256
#define GRID 2048         // 8 blocks/CU target (no-LDS path)
#define NBLOCKS 1024      // fallback grid
#define TOTALP (8 * NN)           // 524288
#define NCHUNKS (TOTALP / CHUNK)  // 8192
#define RA_STRIDE 72              // shorts/point: 9 t-rows x 8 bf16 (16B rows)
#define RB_STRIDE 10              // shorts/point: k=8 column over t, +1 pad
#define NB_STRIDE 10              // u16 indices/point: 9 + 1 pad (20B, 4B-aligned)

typedef float f32x4 __attribute__((ext_vector_type(4)));
typedef float f32x2 __attribute__((ext_vector_type(2)));
typedef unsigned int u32x4 __attribute__((ext_vector_type(4)));
typedef short s16x8 __attribute__((ext_vector_type(8)));
typedef short s16x4 __attribute__((ext_vector_type(4)));

static __device__ __forceinline__ short f2bf(float f) {
    union { __hip_bfloat16 h; short s; } u;
    u.h = __float2bfloat16(f);
    return u.s;
}

// exact bf16->f32
static __device__ __forceinline__ void bf2f2(unsigned int p, float& lo, float& hi) {
    union { unsigned int u; float f; } a, b;
    a.u = p << 16;
    b.u = p & 0xFFFF0000u;
    lo = a.f; hi = b.f;
}
static __device__ __forceinline__ float bf1(unsigned short s) {
    union { unsigned int u; float f; } a;
    a.u = ((unsigned int)s) << 16;
    return a.f;
}

static __device__ __forceinline__ float elu1(float x) {
    float e = __expf(fminf(x, 0.f)) - 1.f;
    return x > 0.f ? x : e;
}

// ---- pre-kernel 1: x (f32) -> xbf (bf16), same layout ----
__global__ __launch_bounds__(THREADS) void xcvt(
    const float* __restrict__ x, unsigned short* __restrict__ xbf)
{
    const size_t i = ((size_t)blockIdx.x * THREADS + threadIdx.x) * 8;
    const f32x4 a = *(const f32x4*)(x + i);
    const f32x4 b = *(const f32x4*)(x + i + 4);
    s16x8 p;
    p[0] = f2bf(a.x); p[1] = f2bf(a.y); p[2] = f2bf(a.z); p[3] = f2bf(a.w);
    p[4] = f2bf(b.x); p[5] = f2bf(b.y); p[6] = f2bf(b.z); p[7] = f2bf(b.w);
    *(s16x8*)(xbf + i) = p;
}

// ---- pre-kernel 2: adjacency -> packed bf16 (recA: k=0..7, recB: k=8) ----
__global__ __launch_bounds__(THREADS) void adjcvt(
    const float* __restrict__ v, const float* __restrict__ aw,
    unsigned short* __restrict__ recA, unsigned short* __restrict__ recB)
{
    const int e = blockIdx.x * THREADS + threadIdx.x;   // over NN*KK exact
    const int n = e / KK;
    const int t = e - n * KK;
    const float* vr = v + n * 8;
    short o[8];
    float s8 = 0.f;
    #pragma unroll
    for (int k = 0; k < KK; ++k) {
        float s = 0.f;
        #pragma unroll
        for (int si = 0; si < 8; ++si)
            s += vr[si] * aw[si * 81 + k * 9 + t];
        if (k < 8) o[k] = f2bf(s); else s8 = s;
    }
    *(s16x8*)(recA + (size_t)n * RA_STRIDE + t * 8) = *(s16x8*)o;
    recB[(size_t)n * RB_STRIDE + t] = (unsigned short)f2bf(s8);
    if (t == 0) recB[(size_t)n * RB_STRIDE + 9] = 0;
}

// ---- pre-kernel 3: nbr int32 -> u16 (indices < NN=65536 by construction) ----
__global__ __launch_bounds__(THREADS) void ncvt(
    const int* __restrict__ nbr, unsigned short* __restrict__ nb16)
{
    const int p = blockIdx.x * THREADS + threadIdx.x;   // over TOTALP exact
    const int* s = nbr + (size_t)p * KK;
    int r[KK];
    #pragma unroll
    for (int k = 0; k < KK; ++k) r[k] = s[k];
    unsigned int* d = (unsigned int*)(nb16 + (size_t)p * NB_STRIDE);
    #pragma unroll
    for (int j = 0; j < 4; ++j)
        d[j] = ((unsigned)r[2*j] & 0xFFFFu) | ((unsigned)r[2*j+1] << 16);
    d[4] = (unsigned)r[8] & 0xFFFFu;
}

// ---- pre-kernel 4: W (f32) -> wbf (bf16), unpadded [64][288] ----
__global__ __launch_bounds__(THREADS) void wcvt(
    const float* __restrict__ W, unsigned short* __restrict__ wbf)
{
    const int i = blockIdx.x * THREADS + threadIdx.x;   // over OO*DD = 18432
    wbf[i] = (unsigned short)f2bf(W[i]);
}

// ================= main kernel: ZERO LDS, max occupancy =================
// Occupancy experiment (R12): R11 ran at 22% occupancy (~7 waves/CU),
// LDS-capped; streaming mixes reach 3.3-3.7 TB/s but gather mixes stick at
// ~2.6 -> hypothesis: miss-concurrency-limited, fix = more resident waves.
//  * W fragments read from GLOBAL bf16 (37 KB, L1/L2-resident, same addrs
//    every chunk). #pragma unroll 1 on t-loop stops the unroller hoisting
//    36 x 16B loads into registers (spill tripwire from R2/R9/R10).
//  * bias read per-chunk in epilogue (L2-hit). No __shared__, no barrier.
//  * nbr as packed u16 (NB_STRIDE=10, dword-aligned): -9 MB fetch.
//  * Everything else = R11: bf16 x gather, bf16 adj records, swapped MFMA,
//    f32x4 stores, unpinned grid-stride, no nontemporal.
__global__ __launch_bounds__(THREADS, 2) void paiconv_nolds(
    const unsigned short* __restrict__ xbf,
    const unsigned short* __restrict__ nb16,
    const unsigned short* __restrict__ recA,
    const unsigned short* __restrict__ recB,
    const unsigned short* __restrict__ wbf,
    const float* __restrict__ bias,
    float* __restrict__ out)
{
    const int lane = threadIdx.x & 63;
    const int wid  = threadIdx.x >> 6;
    const int l15  = lane & 15;       // point within 16-tile (B-col) / W-row (A)
    const int fg   = lane >> 4;       // octet group
    const int fo   = fg * 8;          // f offset (shorts) of this lane's octet
    const int pl   = wid * 16 + l15;  // point within chunk

    const unsigned short* wlane = wbf + (size_t)l15 * DD + fo;

    for (int ci = blockIdx.x; ci < NCHUNKS; ci += GRID) {
        const size_t P = (size_t)ci * CHUNK + pl;
        const int n = (int)(P & (NN - 1));
        const int b = (int)(P >> NLOG);

        // packed u16 neighbor indices (5 aligned dwords)
        const unsigned int* np = (const unsigned int*)(nb16 + P * NB_STRIDE);
        const unsigned int nw0 = np[0], nw1 = np[1], nw2 = np[2], nw3 = np[3], nw4 = np[4];
        int rows[KK];
        rows[0] = nw0 & 0xFFFF; rows[1] = nw0 >> 16;
        rows[2] = nw1 & 0xFFFF; rows[3] = nw1 >> 16;
        rows[4] = nw2 & 0xFFFF; rows[5] = nw2 >> 16;
        rows[6] = nw3 & 0xFFFF; rows[7] = nw3 >> 16;
        rows[8] = nw4 & 0xFFFF;

        // gather neighbor features (bf16): G2[k][i] = {f(fo+2i), f(fo+2i+1)}
        const unsigned short* xb = xbf + (((size_t)b) << NLOG) * FF + fo;
        f32x2 G2[KK][4];
        #pragma unroll
        for (int k = 0; k < KK; ++k) {
            const u32x4 g = *(const u32x4*)(xb + (size_t)rows[k] * FF);
            float l0,h0,l1,h1,l2,h2,l3,h3;
            bf2f2(g.x, l0, h0);
            bf2f2(g.y, l1, h1);
            bf2f2(g.z, l2, h2);
            bf2f2(g.w, l3, h3);
            G2[k][0] = f32x2{l0, h0};
            G2[k][1] = f32x2{l1, h1};
            G2[k][2] = f32x2{l2, h2};
            G2[k][3] = f32x2{l3, h3};
        }

        f32x4 acc0 = {0,0,0,0}, acc1 = {0,0,0,0}, acc2 = {0,0,0,0}, acc3 = {0,0,0,0};

        const unsigned short* ra = recA + (size_t)n * RA_STRIDE;
        const unsigned short* rb = recB + (size_t)n * RB_STRIDE;

        #pragma unroll 1
        for (int t = 0; t < KK; ++t) {
            float a[KK];
            {
                const u32x4 qv = *(const u32x4*)(ra + t * 8);   // 16B aligned
                bf2f2(qv.x, a[0], a[1]);
                bf2f2(qv.y, a[2], a[3]);
                bf2f2(qv.z, a[4], a[5]);
                bf2f2(qv.w, a[6], a[7]);
                a[8] = bf1(rb[t]);
            }

            f32x2 xn2[4] = {{0,0},{0,0},{0,0},{0,0}};
            #pragma unroll
            for (int k = 0; k < KK; ++k) {
                const f32x2 ak = {a[k], a[k]};
                #pragma unroll
                for (int i = 0; i < 4; ++i) xn2[i] += G2[k][i] * ak;
            }
            s16x8 af;
            #pragma unroll
            for (int i = 0; i < 4; ++i) {
                af[2*i]   = f2bf(elu1(xn2[i].x));
                af[2*i+1] = f2bf(elu1(xn2[i].y));
            }

            // W fragments direct from global bf16 (16B aligned; L1/L2-hit)
            const unsigned short* wr = wlane + t * FF;
            const s16x8 b0 = *(const s16x8*)(wr);
            const s16x8 b1 = *(const s16x8*)(wr + 16 * DD);
            const s16x8 b2 = *(const s16x8*)(wr + 32 * DD);
            const s16x8 b3 = *(const s16x8*)(wr + 48 * DD);
            // swapped: A = W tile (row=o within 16-group), B = xn (col=point)
            acc0 = __builtin_amdgcn_mfma_f32_16x16x32_bf16(b0, af, acc0, 0, 0, 0);
            acc1 = __builtin_amdgcn_mfma_f32_16x16x32_bf16(b1, af, acc1, 0, 0, 0);
            acc2 = __builtin_amdgcn_mfma_f32_16x16x32_bf16(b2, af, acc2, 0, 0, 0);
            acc3 = __builtin_amdgcn_mfma_f32_16x16x32_bf16(b3, af, acc3, 0, 0, 0);
        }

        // epilogue: C col(l15)=point P, row(fg*4+reg)=o within 16-group ot.
        const bool zero_pt = ((P & (NN - 1)) == (NN - 1));
        float* orow = out + P * OO + fg * 4;
        #pragma unroll
        for (int ot = 0; ot < 4; ++ot) {
            const f32x4 a = (ot == 0) ? acc0 : (ot == 1) ? acc1 : (ot == 2) ? acc2 : acc3;
            const f32x4 bv = *(const f32x4*)(bias + ot * 16 + fg * 4);
            f32x4 r;
            #pragma unroll
            for (int j = 0; j < 4; ++j)
                r[j] = zero_pt ? 0.f : elu1(a[j] + bv[j]);
            *(f32x4*)(orow + ot * 16) = r;
        }
    }
}

// =============== fallback (no-ws) kernel: R8 f32 path ====================
__global__ __launch_bounds__(THREADS, 2) void paiconv_fb(
    const float* __restrict__ x,
    const int* __restrict__ nbr,
    const float* __restrict__ v,
    const float* __restrict__ aw,
    const float* __restrict__ W,
    const float* __restrict__ bias,
    float* __restrict__ out)
{
    __shared__ short Wl[OO * WSTR];
    __shared__ float BL[OO];
    const int tid = threadIdx.x;
    for (int e = tid; e < OO * DD / 4; e += THREADS) {
        int o = e / 72;
        int d4 = (e - o * 72) * 4;
        const f32x4 wv = *(const f32x4*)(W + o * DD + d4);
        s16x4 p;
        p.x = f2bf(wv.x); p.y = f2bf(wv.y); p.z = f2bf(wv.z); p.w = f2bf(wv.w);
        *(s16x4*)(&Wl[o * WSTR + d4]) = p;
    }
    if (tid < OO) BL[tid] = bias[tid];
    __syncthreads();

    const int lane = tid & 63;
    const int wid  = tid >> 6;
    const int l15  = lane & 15;
    const int fg   = lane >> 4;
    const int fo   = fg * 8;
    const int pl   = wid * 16 + l15;

    for (int ci = blockIdx.x; ci < NCHUNKS; ci += NBLOCKS) {
        const int cbase = ci * CHUNK;
        const int P = cbase + pl;
        const int n = P & (NN - 1);
        const int b = P >> NLOG;
        const int* nip = nbr + (size_t)P * KK;
        const float* xb = x + (((size_t)b) << NLOG) * FF;

        f32x2 G2[KK][4];
        #pragma unroll
        for (int k = 0; k < KK; ++k) {
            const float* src = xb + (size_t)nip[k] * FF + fo;
            const f32x4 g0 = *(const f32x4*)(src);
            const f32x4 g1 = *(const f32x4*)(src + 4);
            G2[k][0] = f32x2{g0.x, g0.y};
            G2[k][1] = f32x2{g0.z, g0.w};
            G2[k][2] = f32x2{g1.x, g1.y};
            G2[k][3] = f32x2{g1.z, g1.w};
        }
        float vr[8];
        #pragma unroll
        for (int si = 0; si < 8; ++si) vr[si] = v[n * 8 + si];

        f32x4 acc0 = {0,0,0,0}, acc1 = {0,0,0,0}, acc2 = {0,0,0,0}, acc3 = {0,0,0,0};
        #pragma unroll
        for (int t = 0; t < KK; ++t) {
            float a[KK];
            #pragma unroll
            for (int k = 0; k < KK; ++k) {
                float s = 0.f;
                #pragma unroll
                for (int si = 0; si < 8; ++si)
                    s += vr[si] * aw[si * 81 + k * 9 + t];
                a[k] = s;
            }
            f32x2 xn2[4] = {{0,0},{0,0},{0,0},{0,0}};
            #pragma unroll
            for (int k = 0; k < KK; ++k) {
                const f32x2 ak = {a[k], a[k]};
                #pragma unroll
                for (int i = 0; i < 4; ++i) xn2[i] += G2[k][i] * ak;
            }
            s16x8 af;
            #pragma unroll
            for (int i = 0; i < 4; ++i) {
                af[2*i]   = f2bf(elu1(xn2[i].x));
                af[2*i+1] = f2bf(elu1(xn2[i].y));
            }
            const short* wrow = &Wl[l15 * WSTR + t * FF + fo];
            s16x8 b0 = *(const s16x8*)(wrow);
            s16x8 b1 = *(const s16x8*)(wrow + 16 * WSTR);
            s16x8 b2 = *(const s16x8*)(wrow + 32 * WSTR);
            s16x8 b3 = *(const s16x8*)(wrow + 48 * WSTR);
            acc0 = __builtin_amdgcn_mfma_f32_16x16x32_bf16(b0, af, acc0, 0, 0, 0);
            acc1 = __builtin_amdgcn_mfma_f32_16x16x32_bf16(b1, af, acc1, 0, 0, 0);
            acc2 = __builtin_amdgcn_mfma_f32_16x16x32_bf16(b2, af, acc2, 0, 0, 0);
            acc3 = __builtin_amdgcn_mfma_f32_16x16x32_bf16(b3, af, acc3, 0, 0, 0);
        }
        const bool zero_pt = ((P & (NN - 1)) == (NN - 1));
        float* orow = out + (size_t)P * OO + fg * 4;
        #pragma unroll
        for (int ot = 0; ot < 4; ++ot) {
            const f32x4 a = (ot == 0) ? acc0 : (ot == 1) ? acc1 : (ot == 2) ? acc2 : acc3;
            const f32x4 bv = *(const f32x4*)&BL[ot * 16 + fg * 4];
            f32x4 r;
            #pragma unroll
            for (int j = 0; j < 4; ++j)
                r[j] = zero_pt ? 0.f : elu1(a[j] + bv[j]);
            *(f32x4*)(orow + ot * 16) = r;
        }
    }
}

extern "C" void kernel_launch(void* const* d_in, const int* in_sizes, int n_in,
                              void* d_out, int out_size, void* d_ws, size_t ws_size,
                              hipStream_t stream) {
    const float* x    = (const float*)d_in[0];
    // d_in[1] = t_vertex (unused in forward)
    const int*   nbr  = (const int*)d_in[2];
    const float* v    = (const float*)d_in[3];
    const float* aw   = (const float*)d_in[4];
    const float* W    = (const float*)d_in[5];
    const float* bias = (const float*)d_in[6];
    float* out = (float*)d_out;

    const size_t xbf_bytes = (size_t)TOTALP * FF * 2;      // 33,554,432
    const size_t ra_bytes  = (size_t)NN * RA_STRIDE * 2;   //  9,437,184
    const size_t rb_bytes  = (size_t)NN * RB_STRIDE * 2;   //  1,310,720
    const size_t nb_bytes  = (size_t)TOTALP * NB_STRIDE * 2; // 10,485,760
    const size_t wb_bytes  = (size_t)OO * DD * 2;          //     36,864
    const size_t need = xbf_bytes + ra_bytes + rb_bytes + nb_bytes + wb_bytes;

    if (ws_size >= need) {
        char* base = (char*)d_ws;
        unsigned short* xbf  = (unsigned short*)base;                          base += xbf_bytes;
        unsigned short* recA = (unsigned short*)base;                          base += ra_bytes;
        unsigned short* recB = (unsigned short*)base;                          base += rb_bytes;
        unsigned short* nb16 = (unsigned short*)base;                          base += nb_bytes;
        unsigned short* wbf  = (unsigned short*)base;

        hipLaunchKernelGGL(xcvt, dim3((TOTALP * FF / 8) / THREADS), dim3(THREADS),
                           0, stream, x, xbf);
        hipLaunchKernelGGL(adjcvt, dim3((NN * KK) / THREADS), dim3(THREADS),
                           0, stream, v, aw, recA, recB);
        hipLaunchKernelGGL(ncvt, dim3(TOTALP / THREADS), dim3(THREADS),
                           0, stream, nbr, nb16);
        hipLaunchKernelGGL(wcvt, dim3((OO * DD) / THREADS), dim3(THREADS),
                           0, stream, W, wbf);
        hipLaunchKernelGGL(paiconv_nolds, dim3(GRID), dim3(THREADS), 0, stream,
                           xbf, nb16, recA, recB, wbf, bias, out);
    } else {
        hipLaunchKernelGGL(paiconv_fb, dim3(NBLOCKS), dim3(THREADS), 0, stream,
                           x, nbr, v, aw, W, bias, out);
    }
}